// Round 1
// baseline (238.995 us; speedup 1.0000x reference)
//
#include <hip/hip_runtime.h>

// ---------------- problem constants ----------------
#define NN 50000
#define NE 800000
#define NF 128

// ---------------- degree count ----------------
__global__ void deg_kernel(const int* __restrict__ ei, unsigned* __restrict__ deg, int E) {
    int e = blockIdx.x * 256 + threadIdx.x;
    if (e < E) atomicAdd(&deg[ei[E + e]], 1u);   // dst = edge_index[1][e]
}

__global__ void dis_kernel(const unsigned* __restrict__ deg, float* __restrict__ dis, int N) {
    int v = blockIdx.x * 256 + threadIdx.x;
    if (v < N) dis[v] = rsqrtf((float)(deg[v] + 1u));  // +1 self-loop
}

// ---------------- 3-kernel exclusive scan of deg -> row_ptr ----------------
__global__ __launch_bounds__(1024) void scanA_kernel(const unsigned* __restrict__ deg,
                                                     unsigned* __restrict__ bsums, int N) {
    int i = blockIdx.x * 1024 + threadIdx.x;
    unsigned v = (i < N) ? deg[i] : 0u;
    for (int d = 1; d < 64; d <<= 1) v += __shfl_xor(v, d, 64);
    __shared__ unsigned ws[16];
    if ((threadIdx.x & 63) == 0) ws[threadIdx.x >> 6] = v;
    __syncthreads();
    if (threadIdx.x == 0) {
        unsigned s = 0;
        for (int k = 0; k < 16; ++k) s += ws[k];
        bsums[blockIdx.x] = s;
    }
}

__global__ void scanB_kernel(unsigned* __restrict__ bsums, int nb) {
    if (threadIdx.x == 0 && blockIdx.x == 0) {
        unsigned run = 0;
        for (int i = 0; i < nb; ++i) { unsigned t = bsums[i]; bsums[i] = run; run += t; }
    }
}

__global__ __launch_bounds__(1024) void scanC_kernel(const unsigned* __restrict__ deg,
                                                     const unsigned* __restrict__ boffs,
                                                     int* __restrict__ row_ptr, int N) {
    int i = blockIdx.x * 1024 + threadIdx.x;
    unsigned orig = (i < N) ? deg[i] : 0u;
    unsigned v = orig;
    int lane = threadIdx.x & 63, wid = threadIdx.x >> 6;
    for (int d = 1; d < 64; d <<= 1) {
        unsigned t = __shfl_up(v, d, 64);
        if (lane >= d) v += t;
    }
    __shared__ unsigned ws[16];
    __shared__ unsigned wo[16];
    if (lane == 63) ws[wid] = v;
    __syncthreads();
    if (threadIdx.x < 16) {
        unsigned s = ws[threadIdx.x];
        for (int d = 1; d < 16; d <<= 1) {
            unsigned t = __shfl_up(s, d, 64);
            if ((int)threadIdx.x >= d) s += t;
        }
        wo[threadIdx.x] = s - ws[threadIdx.x];   // exclusive within block
    }
    __syncthreads();
    unsigned excl = (v - orig) + wo[wid] + boffs[blockIdx.x];
    if (i < N) row_ptr[i] = (int)excl;
    if (i == N - 1) row_ptr[N] = (int)(excl + orig);
}

// ---------------- CSR fill (src + precomputed edge weight) ----------------
__global__ void fill_kernel(const int* __restrict__ ei, const int* __restrict__ row_ptr,
                            unsigned* __restrict__ cursor, const float* __restrict__ dis,
                            int2* __restrict__ edata, int E) {
    int e = blockIdx.x * 256 + threadIdx.x;
    if (e >= E) return;
    int s = ei[e];
    int d = ei[E + e];
    unsigned p = (unsigned)row_ptr[d] + atomicAdd(&cursor[d], 1u);
    float w = dis[s] * dis[d];
    edata[p] = make_int2(s, __float_as_int(w));
}

// ---------------- GEMM: H1 = x @ W1  (f32 vector ALU) ----------------
// Block = 256 threads (4 waves). LDS: swizzled W1^T (64KB) + per-wave 8-row x stage (16KB).
// Wave tile: 8 rows x 128 cols; lane holds cols {l, l+64}; acc[8][2].
__global__ __launch_bounds__(256, 2) void gemm1_kernel(const float* __restrict__ x,
                                                       const float* __restrict__ W1,
                                                       float* __restrict__ H1, int nRows) {
    __shared__ __align__(16) float w1t[128 * 128];   // 64KB, W1^T, XOR-swizzled
    __shared__ __align__(16) float xbuf[4][8][128];  // 16KB
    const int t = threadIdx.x;

    // stage W1^T (transpose + swizzle). thread t -> col c, k-half.
    {
        const int c = t & 127;
        const int k0 = (t >> 7) * 64;
        char* wb = reinterpret_cast<char*>(w1t);
#pragma unroll
        for (int i = 0; i < 16; ++i) {
            int kk = k0 + i * 4;
            float4 w;
            w.x = W1[(kk + 0) * 128 + c];
            w.y = W1[(kk + 1) * 128 + c];
            w.z = W1[(kk + 2) * 128 + c];
            w.w = W1[(kk + 3) * 128 + c];
            int off = (c * 512 + kk * 4) ^ ((c & 7) << 4);
            *reinterpret_cast<float4*>(wb + off) = w;
        }
    }

    const int wid = t >> 6, lane = t & 63;
    const long rowBase = (long)blockIdx.x * 32 + wid * 8;
    const bool haveRows = rowBase < nRows;   // N % 8 == 0 -> whole-wave granularity

    if (haveRows) {
        const float4* gsrc = reinterpret_cast<const float4*>(x + rowBase * NF);
        float4* ldst = reinterpret_cast<float4*>(&xbuf[wid][0][0]);
#pragma unroll
        for (int i = 0; i < 4; ++i) ldst[i * 64 + lane] = gsrc[i * 64 + lane];
    }
    __syncthreads();
    if (!haveRows) return;

    const int c0 = lane, c1 = lane + 64;
    const char* wb = reinterpret_cast<const char*>(w1t);
    const float* xw = &xbuf[wid][0][0];
    float acc[8][2];
#pragma unroll
    for (int r = 0; r < 8; ++r) { acc[r][0] = 0.f; acc[r][1] = 0.f; }

    for (int kk = 0; kk < 128; kk += 4) {
        float4 wA = *reinterpret_cast<const float4*>(wb + ((c0 * 512 + kk * 4) ^ ((c0 & 7) << 4)));
        float4 wB = *reinterpret_cast<const float4*>(wb + ((c1 * 512 + kk * 4) ^ ((c1 & 7) << 4)));
#pragma unroll
        for (int r = 0; r < 8; ++r) {
            float4 xv = *reinterpret_cast<const float4*>(xw + r * NF + kk);
            acc[r][0] = fmaf(xv.x, wA.x, acc[r][0]);
            acc[r][0] = fmaf(xv.y, wA.y, acc[r][0]);
            acc[r][0] = fmaf(xv.z, wA.z, acc[r][0]);
            acc[r][0] = fmaf(xv.w, wA.w, acc[r][0]);
            acc[r][1] = fmaf(xv.x, wB.x, acc[r][1]);
            acc[r][1] = fmaf(xv.y, wB.y, acc[r][1]);
            acc[r][1] = fmaf(xv.z, wB.z, acc[r][1]);
            acc[r][1] = fmaf(xv.w, wB.w, acc[r][1]);
        }
    }

#pragma unroll
    for (int r = 0; r < 8; ++r) {
        long row = rowBase + r;
        H1[row * NF + c0] = acc[r][0];
        H1[row * NF + c1] = acc[r][1];
    }
}

// ---------------- fused layer1 aggregate + self-loop + bias + ReLU + dot(W2) ----------------
// One wave per node; lane l owns features {2l, 2l+1}.
__global__ __launch_bounds__(256) void layer1_kernel(const float* __restrict__ H1,
                                                     const int2* __restrict__ edata,
                                                     const int* __restrict__ row_ptr,
                                                     const float* __restrict__ dis,
                                                     const float* __restrict__ b1,
                                                     const float* __restrict__ W2,
                                                     float* __restrict__ z, int N) {
    const int gw = (blockIdx.x * 256 + threadIdx.x) >> 6;  // global wave id = node
    if (gw >= N) return;
    const int lane = threadIdx.x & 63;
    const int v = gw;
    const int base = row_ptr[v];
    const int end  = row_ptr[v + 1];
    float a0 = 0.f, a1 = 0.f;
    for (int e = base; e < end; ++e) {
        int2 ed = edata[e];                         // wave-uniform broadcast load
        float w = __int_as_float(ed.y);
        float2 hv = *reinterpret_cast<const float2*>(H1 + (long)ed.x * NF + lane * 2);
        a0 = fmaf(hv.x, w, a0);
        a1 = fmaf(hv.y, w, a1);
    }
    const float dv = dis[v];
    const float sw = dv * dv;
    float2 hs = *reinterpret_cast<const float2*>(H1 + (long)v * NF + lane * 2);
    float2 bb = *reinterpret_cast<const float2*>(b1 + lane * 2);
    float h0 = a0 + hs.x * sw + bb.x;
    float h1 = a1 + hs.y * sw + bb.y;
    h0 = h0 > 0.f ? h0 : 0.f;
    h1 = h1 > 0.f ? h1 : 0.f;
    float2 w2 = *reinterpret_cast<const float2*>(W2 + lane * 2);
    float p = fmaf(h0, w2.x, h1 * w2.y);
    for (int d = 1; d < 64; d <<= 1) p += __shfl_xor(p, d, 64);
    if (lane == 0) z[v] = p;
}

// ---------------- layer2 aggregate (scalar) + finalize ----------------
__global__ void final_kernel(const float* __restrict__ z, const int2* __restrict__ edata,
                             const int* __restrict__ row_ptr, const float* __restrict__ dis,
                             const float* __restrict__ b2, float* __restrict__ out, int N) {
    int v = blockIdx.x * 256 + threadIdx.x;
    if (v >= N) return;
    const int base = row_ptr[v];
    const int end  = row_ptr[v + 1];
    float acc = 0.f;
    for (int e = base; e < end; ++e) {
        int2 ed = edata[e];
        acc = fmaf(z[ed.x], __int_as_float(ed.y), acc);
    }
    float dv = dis[v];
    out[v] = acc + z[v] * dv * dv + b2[0];
}

// ---------------- launch ----------------
extern "C" void kernel_launch(void* const* d_in, const int* in_sizes, int n_in,
                              void* d_out, int out_size, void* d_ws, size_t ws_size,
                              hipStream_t stream) {
    const float* x  = (const float*)d_in[0];
    const int*   ei = (const int*)d_in[1];
    const float* W1 = (const float*)d_in[2];
    const float* b1 = (const float*)d_in[3];
    const float* W2 = (const float*)d_in[4];
    const float* b2 = (const float*)d_in[5];
    float* out = (float*)d_out;

    char* ws = (char*)d_ws;
    size_t o = 0;
    auto alloc = [&](size_t bytes) -> void* {
        void* p = ws + o;
        o += (bytes + 255) & ~(size_t)255;
        return p;
    };
    unsigned* deg    = (unsigned*)alloc((size_t)NN * 4);
    unsigned* cursor = (unsigned*)alloc((size_t)NN * 4);
    float*    dis    = (float*)alloc((size_t)NN * 4);
    int*      row_ptr= (int*)alloc((size_t)(NN + 1) * 4);
    unsigned* bsums  = (unsigned*)alloc(64 * 4);
    int2*     edata  = (int2*)alloc((size_t)NE * 8);
    float*    z      = (float*)alloc((size_t)NN * 4);
    float*    H1     = (float*)alloc((size_t)NN * NF * 4);

    hipMemsetAsync(deg, 0, (size_t)NN * 4, stream);
    hipMemsetAsync(cursor, 0, (size_t)NN * 4, stream);

    deg_kernel<<<(NE + 255) / 256, 256, 0, stream>>>(ei, deg, NE);
    dis_kernel<<<(NN + 255) / 256, 256, 0, stream>>>(deg, dis, NN);

    const int SB = (NN + 1023) / 1024;  // 49
    scanA_kernel<<<SB, 1024, 0, stream>>>(deg, bsums, NN);
    scanB_kernel<<<1, 64, 0, stream>>>(bsums, SB);
    scanC_kernel<<<SB, 1024, 0, stream>>>(deg, bsums, row_ptr, NN);

    fill_kernel<<<(NE + 255) / 256, 256, 0, stream>>>(ei, row_ptr, cursor, dis, edata, NE);

    gemm1_kernel<<<(NN + 31) / 32, 256, 0, stream>>>(x, W1, H1, NN);

    layer1_kernel<<<(NN * 64 + 255) / 256, 256, 0, stream>>>(H1, edata, row_ptr, dis, b1, W2, z, NN);

    final_kernel<<<(NN + 255) / 256, 256, 0, stream>>>(z, edata, row_ptr, dis, b2, out, NN);
}

// Round 2
// 198.938 us; speedup vs baseline: 1.2014x; 1.2014x over previous
//
#include <hip/hip_runtime.h>

// ---------------- problem constants ----------------
#define NN 50000
#define NE 800000
#define NF 128

// ---------------- degree count ----------------
__global__ void deg_kernel(const int* __restrict__ ei, unsigned* __restrict__ deg, int E) {
    int e = blockIdx.x * 256 + threadIdx.x;
    if (e < E) atomicAdd(&deg[ei[E + e]], 1u);   // dst = edge_index[1][e]
}

__global__ void dis_kernel(const unsigned* __restrict__ deg, float* __restrict__ dis, int N) {
    int v = blockIdx.x * 256 + threadIdx.x;
    if (v < N) dis[v] = rsqrtf((float)(deg[v] + 1u));  // +1 self-loop
}

// ---------------- 3-kernel exclusive scan of deg -> row_ptr ----------------
__global__ __launch_bounds__(1024) void scanA_kernel(const unsigned* __restrict__ deg,
                                                     unsigned* __restrict__ bsums, int N) {
    int i = blockIdx.x * 1024 + threadIdx.x;
    unsigned v = (i < N) ? deg[i] : 0u;
    for (int d = 1; d < 64; d <<= 1) v += __shfl_xor(v, d, 64);
    __shared__ unsigned ws[16];
    if ((threadIdx.x & 63) == 0) ws[threadIdx.x >> 6] = v;
    __syncthreads();
    if (threadIdx.x == 0) {
        unsigned s = 0;
        for (int k = 0; k < 16; ++k) s += ws[k];
        bsums[blockIdx.x] = s;
    }
}

__global__ void scanB_kernel(unsigned* __restrict__ bsums, int nb) {
    if (threadIdx.x == 0 && blockIdx.x == 0) {
        unsigned run = 0;
        for (int i = 0; i < nb; ++i) { unsigned t = bsums[i]; bsums[i] = run; run += t; }
    }
}

__global__ __launch_bounds__(1024) void scanC_kernel(const unsigned* __restrict__ deg,
                                                     const unsigned* __restrict__ boffs,
                                                     int* __restrict__ row_ptr, int N) {
    int i = blockIdx.x * 1024 + threadIdx.x;
    unsigned orig = (i < N) ? deg[i] : 0u;
    unsigned v = orig;
    int lane = threadIdx.x & 63, wid = threadIdx.x >> 6;
    for (int d = 1; d < 64; d <<= 1) {
        unsigned t = __shfl_up(v, d, 64);
        if (lane >= d) v += t;
    }
    __shared__ unsigned ws[16];
    __shared__ unsigned wo[16];
    if (lane == 63) ws[wid] = v;
    __syncthreads();
    if (threadIdx.x < 16) {
        unsigned s = ws[threadIdx.x];
        for (int d = 1; d < 16; d <<= 1) {
            unsigned t = __shfl_up(s, d, 64);
            if ((int)threadIdx.x >= d) s += t;
        }
        wo[threadIdx.x] = s - ws[threadIdx.x];   // exclusive within block
    }
    __syncthreads();
    unsigned excl = (v - orig) + wo[wid] + boffs[blockIdx.x];
    if (i < N) row_ptr[i] = (int)excl;
    if (i == N - 1) row_ptr[N] = (int)(excl + orig);
}

// ---------------- CSR fill (src + precomputed edge weight) ----------------
__global__ void fill_kernel(const int* __restrict__ ei, const int* __restrict__ row_ptr,
                            unsigned* __restrict__ cursor, const float* __restrict__ dis,
                            int2* __restrict__ edata, int E) {
    int e = blockIdx.x * 256 + threadIdx.x;
    if (e >= E) return;
    int s = ei[e];
    int d = ei[E + e];
    unsigned p = (unsigned)row_ptr[d] + atomicAdd(&cursor[d], 1u);
    float w = dis[s] * dis[d];
    edata[p] = make_int2(s, __float_as_int(w));
}

// ---------------- GEMM: H1 = x @ W1  (f32 vector ALU) ----------------
__global__ __launch_bounds__(256, 2) void gemm1_kernel(const float* __restrict__ x,
                                                       const float* __restrict__ W1,
                                                       float* __restrict__ H1, int nRows) {
    __shared__ __align__(16) float w1t[128 * 128];   // 64KB, W1^T, XOR-swizzled
    __shared__ __align__(16) float xbuf[4][8][128];  // 16KB
    const int t = threadIdx.x;

    {
        const int c = t & 127;
        const int k0 = (t >> 7) * 64;
        char* wb = reinterpret_cast<char*>(w1t);
#pragma unroll
        for (int i = 0; i < 16; ++i) {
            int kk = k0 + i * 4;
            float4 w;
            w.x = W1[(kk + 0) * 128 + c];
            w.y = W1[(kk + 1) * 128 + c];
            w.z = W1[(kk + 2) * 128 + c];
            w.w = W1[(kk + 3) * 128 + c];
            int off = (c * 512 + kk * 4) ^ ((c & 7) << 4);
            *reinterpret_cast<float4*>(wb + off) = w;
        }
    }

    const int wid = t >> 6, lane = t & 63;
    const long rowBase = (long)blockIdx.x * 32 + wid * 8;
    const bool haveRows = rowBase < nRows;

    if (haveRows) {
        const float4* gsrc = reinterpret_cast<const float4*>(x + rowBase * NF);
        float4* ldst = reinterpret_cast<float4*>(&xbuf[wid][0][0]);
#pragma unroll
        for (int i = 0; i < 4; ++i) ldst[i * 64 + lane] = gsrc[i * 64 + lane];
    }
    __syncthreads();
    if (!haveRows) return;

    const int c0 = lane, c1 = lane + 64;
    const char* wb = reinterpret_cast<const char*>(w1t);
    const float* xw = &xbuf[wid][0][0];
    float acc[8][2];
#pragma unroll
    for (int r = 0; r < 8; ++r) { acc[r][0] = 0.f; acc[r][1] = 0.f; }

    for (int kk = 0; kk < 128; kk += 4) {
        float4 wA = *reinterpret_cast<const float4*>(wb + ((c0 * 512 + kk * 4) ^ ((c0 & 7) << 4)));
        float4 wB = *reinterpret_cast<const float4*>(wb + ((c1 * 512 + kk * 4) ^ ((c1 & 7) << 4)));
#pragma unroll
        for (int r = 0; r < 8; ++r) {
            float4 xv = *reinterpret_cast<const float4*>(xw + r * NF + kk);
            acc[r][0] = fmaf(xv.x, wA.x, acc[r][0]);
            acc[r][0] = fmaf(xv.y, wA.y, acc[r][0]);
            acc[r][0] = fmaf(xv.z, wA.z, acc[r][0]);
            acc[r][0] = fmaf(xv.w, wA.w, acc[r][0]);
            acc[r][1] = fmaf(xv.x, wB.x, acc[r][1]);
            acc[r][1] = fmaf(xv.y, wB.y, acc[r][1]);
            acc[r][1] = fmaf(xv.z, wB.z, acc[r][1]);
            acc[r][1] = fmaf(xv.w, wB.w, acc[r][1]);
        }
    }

#pragma unroll
    for (int r = 0; r < 8; ++r) {
        long row = rowBase + r;
        H1[row * NF + c0] = acc[r][0];
        H1[row * NF + c1] = acc[r][1];
    }
}

// ---------------- fused layer1: aggregate + self-loop + bias + ReLU + dot(W2) ----------------
// One wave per node; lane l owns features {2l, 2l+1}.
// MLP redesign: coalesced edata lane-load per 64-edge chunk, shfl broadcast,
// 8-wide batched independent H1 gathers.
__global__ __launch_bounds__(256) void layer1_kernel(const float* __restrict__ H1,
                                                     const int2* __restrict__ edata,
                                                     const int* __restrict__ row_ptr,
                                                     const float* __restrict__ dis,
                                                     const float* __restrict__ b1,
                                                     const float* __restrict__ W2,
                                                     float* __restrict__ z, int N) {
    const int v = (blockIdx.x * 256 + threadIdx.x) >> 6;
    if (v >= N) return;
    const int lane = threadIdx.x & 63;
    const int base = row_ptr[v];
    const int end  = row_ptr[v + 1];
    float a0 = 0.f, a1 = 0.f;

    for (int cb = base; cb < end; cb += 64) {
        const int m = min(64, end - cb);
        int es = 0; float ew = 0.f;
        if (cb + lane < end) {
            int2 ed = edata[cb + lane];            // coalesced
            es = ed.x; ew = __int_as_float(ed.y);
        }
        int i = 0;
        for (; i + 8 <= m; i += 8) {
            int s[8]; float w[8]; float2 h[8];
#pragma unroll
            for (int j = 0; j < 8; ++j) { s[j] = __shfl(es, i + j); w[j] = __shfl(ew, i + j); }
#pragma unroll
            for (int j = 0; j < 8; ++j)
                h[j] = *reinterpret_cast<const float2*>(H1 + (long)s[j] * NF + lane * 2);
#pragma unroll
            for (int j = 0; j < 8; ++j) { a0 = fmaf(h[j].x, w[j], a0); a1 = fmaf(h[j].y, w[j], a1); }
        }
        for (; i + 4 <= m; i += 4) {
            int s[4]; float w[4]; float2 h[4];
#pragma unroll
            for (int j = 0; j < 4; ++j) { s[j] = __shfl(es, i + j); w[j] = __shfl(ew, i + j); }
#pragma unroll
            for (int j = 0; j < 4; ++j)
                h[j] = *reinterpret_cast<const float2*>(H1 + (long)s[j] * NF + lane * 2);
#pragma unroll
            for (int j = 0; j < 4; ++j) { a0 = fmaf(h[j].x, w[j], a0); a1 = fmaf(h[j].y, w[j], a1); }
        }
        for (; i < m; ++i) {
            int sj = __shfl(es, i); float wj = __shfl(ew, i);
            float2 hj = *reinterpret_cast<const float2*>(H1 + (long)sj * NF + lane * 2);
            a0 = fmaf(hj.x, wj, a0); a1 = fmaf(hj.y, wj, a1);
        }
    }

    const float dv = dis[v];
    const float sw = dv * dv;
    float2 hs = *reinterpret_cast<const float2*>(H1 + (long)v * NF + lane * 2);
    float2 bb = *reinterpret_cast<const float2*>(b1 + lane * 2);
    float h0 = a0 + hs.x * sw + bb.x;
    float h1 = a1 + hs.y * sw + bb.y;
    h0 = h0 > 0.f ? h0 : 0.f;
    h1 = h1 > 0.f ? h1 : 0.f;
    float2 w2 = *reinterpret_cast<const float2*>(W2 + lane * 2);
    float p = fmaf(h0, w2.x, h1 * w2.y);
    for (int d = 1; d < 64; d <<= 1) p += __shfl_xor(p, d, 64);
    if (lane == 0) z[v] = p;
}

// ---------------- layer2 aggregate (scalar) + finalize ----------------
// 8 lanes per node, edge-strided; 3-step shfl_xor group reduce.
__global__ __launch_bounds__(256) void final_kernel(const float* __restrict__ z,
                                                    const int2* __restrict__ edata,
                                                    const int* __restrict__ row_ptr,
                                                    const float* __restrict__ dis,
                                                    const float* __restrict__ b2,
                                                    float* __restrict__ out, int N) {
    const int g = (blockIdx.x * 256 + threadIdx.x) >> 3;   // node
    if (g >= N) return;
    const int sl = threadIdx.x & 7;
    const int base = row_ptr[g];
    const int end  = row_ptr[g + 1];
    float acc = 0.f;
    for (int e = base + sl; e < end; e += 8) {
        int2 ed = edata[e];
        acc = fmaf(z[ed.x], __int_as_float(ed.y), acc);
    }
#pragma unroll
    for (int d = 1; d < 8; d <<= 1) acc += __shfl_xor(acc, d, 64);
    if (sl == 0) {
        float dv = dis[g];
        out[g] = acc + z[g] * dv * dv + b2[0];
    }
}

// ---------------- launch ----------------
extern "C" void kernel_launch(void* const* d_in, const int* in_sizes, int n_in,
                              void* d_out, int out_size, void* d_ws, size_t ws_size,
                              hipStream_t stream) {
    const float* x  = (const float*)d_in[0];
    const int*   ei = (const int*)d_in[1];
    const float* W1 = (const float*)d_in[2];
    const float* b1 = (const float*)d_in[3];
    const float* W2 = (const float*)d_in[4];
    const float* b2 = (const float*)d_in[5];
    float* out = (float*)d_out;

    char* ws = (char*)d_ws;
    size_t o = 0;
    auto alloc = [&](size_t bytes) -> void* {
        void* p = ws + o;
        o += (bytes + 255) & ~(size_t)255;
        return p;
    };
    unsigned* deg    = (unsigned*)alloc((size_t)NN * 4);
    unsigned* cursor = (unsigned*)alloc((size_t)NN * 4);
    float*    dis    = (float*)alloc((size_t)NN * 4);
    int*      row_ptr= (int*)alloc((size_t)(NN + 1) * 4);
    unsigned* bsums  = (unsigned*)alloc(64 * 4);
    int2*     edata  = (int2*)alloc((size_t)NE * 8);
    float*    z      = (float*)alloc((size_t)NN * 4);
    float*    H1     = (float*)alloc((size_t)NN * NF * 4);

    hipMemsetAsync(deg, 0, (size_t)NN * 4, stream);
    hipMemsetAsync(cursor, 0, (size_t)NN * 4, stream);

    deg_kernel<<<(NE + 255) / 256, 256, 0, stream>>>(ei, deg, NE);
    dis_kernel<<<(NN + 255) / 256, 256, 0, stream>>>(deg, dis, NN);

    const int SB = (NN + 1023) / 1024;  // 49
    scanA_kernel<<<SB, 1024, 0, stream>>>(deg, bsums, NN);
    scanB_kernel<<<1, 64, 0, stream>>>(bsums, SB);
    scanC_kernel<<<SB, 1024, 0, stream>>>(deg, bsums, row_ptr, NN);

    fill_kernel<<<(NE + 255) / 256, 256, 0, stream>>>(ei, row_ptr, cursor, dis, edata, NE);

    gemm1_kernel<<<(NN + 31) / 32, 256, 0, stream>>>(x, W1, H1, NN);

    layer1_kernel<<<(NN * 64 + 255) / 256, 256, 0, stream>>>(H1, edata, row_ptr, dis, b1, W2, z, NN);

    final_kernel<<<(NN * 8 + 255) / 256, 256, 0, stream>>>(z, edata, row_ptr, dis, b2, out, NN);
}

// Round 3
// 172.283 us; speedup vs baseline: 1.3872x; 1.1547x over previous
//
#include <hip/hip_runtime.h>

// ---------------- problem constants ----------------
#define NN 50000
#define NE 800000
#define NF 128

__device__ __forceinline__ unsigned bf16rne(float f) {
    unsigned u = __float_as_uint(f);
    return (u + 0x7FFFu + ((u >> 16) & 1u)) >> 16;
}

// ---------------- degree count ----------------
__global__ void deg_kernel(const int* __restrict__ ei, unsigned* __restrict__ deg, int E) {
    int e = blockIdx.x * 256 + threadIdx.x;
    if (e < E) atomicAdd(&deg[ei[E + e]], 1u);   // dst = edge_index[1][e]
}

__global__ void dis_kernel(const unsigned* __restrict__ deg, float* __restrict__ dis, int N) {
    int v = blockIdx.x * 256 + threadIdx.x;
    if (v < N) dis[v] = rsqrtf((float)(deg[v] + 1u));  // +1 self-loop
}

// ---------------- scan: deg -> row_ptr ----------------
__global__ __launch_bounds__(1024) void scanA_kernel(const unsigned* __restrict__ deg,
                                                     unsigned* __restrict__ bsums, int N) {
    int i = blockIdx.x * 1024 + threadIdx.x;
    unsigned v = (i < N) ? deg[i] : 0u;
    for (int d = 1; d < 64; d <<= 1) v += __shfl_xor(v, d, 64);
    __shared__ unsigned ws[16];
    if ((threadIdx.x & 63) == 0) ws[threadIdx.x >> 6] = v;
    __syncthreads();
    if (threadIdx.x == 0) {
        unsigned s = 0;
        for (int k = 0; k < 16; ++k) s += ws[k];
        bsums[blockIdx.x] = s;
    }
}

// 64-lane shfl exclusive scan over block sums (nb <= 64)
__global__ void scanB_kernel(unsigned* __restrict__ bsums, int nb) {
    int lane = threadIdx.x & 63;
    unsigned v = (lane < nb) ? bsums[lane] : 0u;
    unsigned orig = v;
    for (int d = 1; d < 64; d <<= 1) {
        unsigned t = __shfl_up(v, d, 64);
        if (lane >= d) v += t;
    }
    if (lane < nb) bsums[lane] = v - orig;
}

__global__ __launch_bounds__(1024) void scanC_kernel(const unsigned* __restrict__ deg,
                                                     const unsigned* __restrict__ boffs,
                                                     int* __restrict__ row_ptr, int N) {
    int i = blockIdx.x * 1024 + threadIdx.x;
    unsigned orig = (i < N) ? deg[i] : 0u;
    unsigned v = orig;
    int lane = threadIdx.x & 63, wid = threadIdx.x >> 6;
    for (int d = 1; d < 64; d <<= 1) {
        unsigned t = __shfl_up(v, d, 64);
        if (lane >= d) v += t;
    }
    __shared__ unsigned ws[16];
    __shared__ unsigned wo[16];
    if (lane == 63) ws[wid] = v;
    __syncthreads();
    if (threadIdx.x < 16) {
        unsigned s = ws[threadIdx.x];
        for (int d = 1; d < 16; d <<= 1) {
            unsigned t = __shfl_up(s, d, 64);
            if ((int)threadIdx.x >= d) s += t;
        }
        wo[threadIdx.x] = s - ws[threadIdx.x];
    }
    __syncthreads();
    unsigned excl = (v - orig) + wo[wid] + boffs[blockIdx.x];
    if (i < N) row_ptr[i] = (int)excl;
    if (i == N - 1) row_ptr[N] = (int)(excl + orig);
}

// ---------------- CSR fill (src only; weights recomputed by consumers) ----------------
__global__ void fill_kernel(const int* __restrict__ ei, const int* __restrict__ row_ptr,
                            unsigned* __restrict__ cursor, int* __restrict__ esrc, int E) {
    int e = blockIdx.x * 256 + threadIdx.x;
    if (e >= E) return;
    int s = ei[e];
    int d = ei[E + e];
    unsigned p = (unsigned)row_ptr[d] + atomicAdd(&cursor[d], 1u);
    esrc[p] = s;
}

// ---------------- GEMM: H1 = x @ W1 (f32 math, bf16x2-packed store) ----------------
// Lane owns cols {2l, 2l+1}; acc[8][2]; swizzle keyed on (c>>1)&7 so the col-pair shares it.
__global__ __launch_bounds__(256, 2) void gemm1_kernel(const float* __restrict__ x,
                                                       const float* __restrict__ W1,
                                                       unsigned* __restrict__ H1b, int nRows) {
    __shared__ __align__(16) float w1t[128 * 128];   // 64KB, W1^T, XOR-swizzled
    __shared__ __align__(16) float xbuf[4][8][128];  // 16KB
    const int t = threadIdx.x;

    {
        const int c = t & 127;
        const int k0 = (t >> 7) * 64;
        char* wb = reinterpret_cast<char*>(w1t);
#pragma unroll
        for (int i = 0; i < 16; ++i) {
            int kk = k0 + i * 4;
            float4 w;
            w.x = W1[(kk + 0) * 128 + c];
            w.y = W1[(kk + 1) * 128 + c];
            w.z = W1[(kk + 2) * 128 + c];
            w.w = W1[(kk + 3) * 128 + c];
            int off = (c * 512 + kk * 4) ^ (((c >> 1) & 7) << 4);
            *reinterpret_cast<float4*>(wb + off) = w;
        }
    }

    const int wid = t >> 6, lane = t & 63;
    const long rowBase = (long)blockIdx.x * 32 + wid * 8;
    const bool haveRows = rowBase < nRows;

    if (haveRows) {
        const float4* gsrc = reinterpret_cast<const float4*>(x + rowBase * NF);
        float4* ldst = reinterpret_cast<float4*>(&xbuf[wid][0][0]);
#pragma unroll
        for (int i = 0; i < 4; ++i) ldst[i * 64 + lane] = gsrc[i * 64 + lane];
    }
    __syncthreads();
    if (!haveRows) return;

    const int c0 = 2 * lane;                      // col pair {2l, 2l+1}
    const char* wb = reinterpret_cast<const char*>(w1t);
    const float* xw = &xbuf[wid][0][0];
    float acc[8][2];
#pragma unroll
    for (int r = 0; r < 8; ++r) { acc[r][0] = 0.f; acc[r][1] = 0.f; }

    for (int kk = 0; kk < 128; kk += 4) {
        int offA = (c0 * 512 + kk * 4) ^ ((lane & 7) << 4);
        float4 wA = *reinterpret_cast<const float4*>(wb + offA);
        float4 wB = *reinterpret_cast<const float4*>(wb + offA + 512);
#pragma unroll
        for (int r = 0; r < 8; ++r) {
            float4 xv = *reinterpret_cast<const float4*>(xw + r * NF + kk);
            acc[r][0] = fmaf(xv.x, wA.x, acc[r][0]);
            acc[r][0] = fmaf(xv.y, wA.y, acc[r][0]);
            acc[r][0] = fmaf(xv.z, wA.z, acc[r][0]);
            acc[r][0] = fmaf(xv.w, wA.w, acc[r][0]);
            acc[r][1] = fmaf(xv.x, wB.x, acc[r][1]);
            acc[r][1] = fmaf(xv.y, wB.y, acc[r][1]);
            acc[r][1] = fmaf(xv.z, wB.z, acc[r][1]);
            acc[r][1] = fmaf(xv.w, wB.w, acc[r][1]);
        }
    }

#pragma unroll
    for (int r = 0; r < 8; ++r) {
        long row = rowBase + r;
        H1b[row * 64 + lane] = bf16rne(acc[r][0]) | (bf16rne(acc[r][1]) << 16);
    }
}

// ---------------- fused layer1: aggregate + self + bias + ReLU + dot(W2), bf16 gathers ----------------
// One wave per node. Half-wave (32 lanes x 8B) gathers one 256B bf16 row -> 2 edges/iter.
// Lane (l&31) owns features {4l', 4l'+1, 4l'+2, 4l'+3}. Writes zd[v] = dis[v]*z[v].
__global__ __launch_bounds__(256) void layer1_kernel(const unsigned* __restrict__ H1b,
                                                     const int* __restrict__ esrc,
                                                     const int* __restrict__ row_ptr,
                                                     const float* __restrict__ dis,
                                                     const float* __restrict__ b1,
                                                     const float* __restrict__ W2,
                                                     float* __restrict__ zd, int N) {
    const int v = (blockIdx.x * 256 + threadIdx.x) >> 6;
    if (v >= N) return;
    const int lane = threadIdx.x & 63;
    const int half = lane >> 5;
    const int sub = lane & 31;
    const int base = row_ptr[v];
    const int end  = row_ptr[v + 1];
    const char* hb = reinterpret_cast<const char*>(H1b);

    float a0 = 0.f, a1 = 0.f, a2 = 0.f, a3 = 0.f;

    for (int cb = base; cb < end; cb += 64) {
        const int m = min(64, end - cb);
        int es = 0; float ds_ = 0.f;
        if (cb + lane < end) {
            es = esrc[cb + lane];                  // coalesced
            ds_ = dis[es];                          // L2-resident 200KB
        }
        const int pc = (m + 1) >> 1;               // edge pairs
        int i = 0;
        for (; i + 8 <= pc; i += 8) {
            float w[8]; uint2 u[8];
#pragma unroll
            for (int j = 0; j < 8; ++j) {
                int idx = 2 * (i + j) + half;
                int sj = __shfl(es, idx);
                w[j] = __shfl(ds_, idx);
                u[j] = *reinterpret_cast<const uint2*>(hb + (size_t)(unsigned)sj * 256 + sub * 8);
            }
#pragma unroll
            for (int j = 0; j < 8; ++j) {
                a0 = fmaf(__uint_as_float(u[j].x << 16), w[j], a0);
                a1 = fmaf(__uint_as_float(u[j].x & 0xffff0000u), w[j], a1);
                a2 = fmaf(__uint_as_float(u[j].y << 16), w[j], a2);
                a3 = fmaf(__uint_as_float(u[j].y & 0xffff0000u), w[j], a3);
            }
        }
        for (; i < pc; ++i) {
            int idx = 2 * i + half;
            int sj = __shfl(es, idx);
            float wj = __shfl(ds_, idx);
            uint2 uj = *reinterpret_cast<const uint2*>(hb + (size_t)(unsigned)sj * 256 + sub * 8);
            a0 = fmaf(__uint_as_float(uj.x << 16), wj, a0);
            a1 = fmaf(__uint_as_float(uj.x & 0xffff0000u), wj, a1);
            a2 = fmaf(__uint_as_float(uj.y << 16), wj, a2);
            a3 = fmaf(__uint_as_float(uj.y & 0xffff0000u), wj, a3);
        }
    }

    // combine the two halves (each covered disjoint edges for the same features)
    a0 += __shfl_xor(a0, 32, 64);
    a1 += __shfl_xor(a1, 32, 64);
    a2 += __shfl_xor(a2, 32, 64);
    a3 += __shfl_xor(a3, 32, 64);

    const float dv = dis[v];
    const float sw = dv * dv;
    uint2 hs = *reinterpret_cast<const uint2*>(hb + (size_t)v * 256 + sub * 8);
    float4 bb = *reinterpret_cast<const float4*>(b1 + sub * 4);
    float4 w2 = *reinterpret_cast<const float4*>(W2 + sub * 4);
    float h0 = fmaf(dv, a0, fmaf(sw, __uint_as_float(hs.x << 16), bb.x));
    float h1 = fmaf(dv, a1, fmaf(sw, __uint_as_float(hs.x & 0xffff0000u), bb.y));
    float h2 = fmaf(dv, a2, fmaf(sw, __uint_as_float(hs.y << 16), bb.z));
    float h3 = fmaf(dv, a3, fmaf(sw, __uint_as_float(hs.y & 0xffff0000u), bb.w));
    h0 = h0 > 0.f ? h0 : 0.f;
    h1 = h1 > 0.f ? h1 : 0.f;
    h2 = h2 > 0.f ? h2 : 0.f;
    h3 = h3 > 0.f ? h3 : 0.f;
    float p = fmaf(h0, w2.x, fmaf(h1, w2.y, fmaf(h2, w2.z, h3 * w2.w)));
    for (int d = 1; d < 64; d <<= 1) p += __shfl_xor(p, d, 64);
    if (lane == 0) zd[v] = 0.5f * dv * p;   // features double-counted across halves
}

// ---------------- layer2 aggregate (scalar zd gather) + finalize ----------------
__global__ __launch_bounds__(256) void final_kernel(const float* __restrict__ zd,
                                                    const int* __restrict__ esrc,
                                                    const int* __restrict__ row_ptr,
                                                    const float* __restrict__ dis,
                                                    const float* __restrict__ b2,
                                                    float* __restrict__ out, int N) {
    const int g = (blockIdx.x * 256 + threadIdx.x) >> 3;
    if (g >= N) return;
    const int sl = threadIdx.x & 7;
    const int base = row_ptr[g];
    const int end  = row_ptr[g + 1];
    float acc = 0.f;
    for (int e = base + sl; e < end; e += 8) acc += zd[esrc[e]];
#pragma unroll
    for (int d = 1; d < 8; d <<= 1) acc += __shfl_xor(acc, d, 64);
    if (sl == 0) out[g] = fmaf(dis[g], acc + zd[g], b2[0]);
}

// ---------------- launch ----------------
extern "C" void kernel_launch(void* const* d_in, const int* in_sizes, int n_in,
                              void* d_out, int out_size, void* d_ws, size_t ws_size,
                              hipStream_t stream) {
    const float* x  = (const float*)d_in[0];
    const int*   ei = (const int*)d_in[1];
    const float* W1 = (const float*)d_in[2];
    const float* b1 = (const float*)d_in[3];
    const float* W2 = (const float*)d_in[4];
    const float* b2 = (const float*)d_in[5];
    float* out = (float*)d_out;

    char* ws = (char*)d_ws;
    size_t o = 0;
    auto alloc = [&](size_t bytes) -> void* {
        void* p = ws + o;
        o += (bytes + 255) & ~(size_t)255;
        return p;
    };
    unsigned* deg    = (unsigned*)alloc((size_t)NN * 4);
    unsigned* cursor = (unsigned*)alloc((size_t)NN * 4);
    float*    dis    = (float*)alloc((size_t)NN * 4);
    int*      row_ptr= (int*)alloc((size_t)(NN + 1) * 4);
    unsigned* bsums  = (unsigned*)alloc(64 * 4);
    int*      esrc   = (int*)alloc((size_t)NE * 4);
    float*    zd     = (float*)alloc((size_t)NN * 4);
    unsigned* H1b    = (unsigned*)alloc((size_t)NN * NF * 2);  // bf16x2 packed

    hipMemsetAsync(deg, 0, (size_t)NN * 4, stream);
    hipMemsetAsync(cursor, 0, (size_t)NN * 4, stream);

    deg_kernel<<<(NE + 255) / 256, 256, 0, stream>>>(ei, deg, NE);
    dis_kernel<<<(NN + 255) / 256, 256, 0, stream>>>(deg, dis, NN);

    const int SB = (NN + 1023) / 1024;  // 49
    scanA_kernel<<<SB, 1024, 0, stream>>>(deg, bsums, NN);
    scanB_kernel<<<1, 64, 0, stream>>>(bsums, SB);
    scanC_kernel<<<SB, 1024, 0, stream>>>(deg, bsums, row_ptr, NN);

    fill_kernel<<<(NE + 255) / 256, 256, 0, stream>>>(ei, row_ptr, cursor, esrc, NE);

    gemm1_kernel<<<(NN + 31) / 32, 256, 0, stream>>>(x, W1, H1b, NN);

    layer1_kernel<<<(NN * 64 + 255) / 256, 256, 0, stream>>>(H1b, esrc, row_ptr, dis, b1, W2, zd, NN);

    final_kernel<<<(NN * 8 + 255) / 256, 256, 0, stream>>>(zd, esrc, row_ptr, dis, b2, out, NN);
}

// Round 4
// 123.255 us; speedup vs baseline: 1.9390x; 1.3978x over previous
//
#include <hip/hip_runtime.h>

// ---------------- problem constants ----------------
#define NN 50000
#define NE 800000
#define NF 128
#define NB 196        // ceil(NN/256) buckets of 256 nodes
#define BSH 8         // bucket = dst >> 8
#define BNODES 256

__device__ __forceinline__ unsigned bf16rne(float f) {
    unsigned u = __float_as_uint(f);
    return (u + 0x7FFFu + ((u >> 16) & 1u)) >> 16;
}

// ---------------- K1: bucket histogram (LDS-binned) ----------------
__global__ __launch_bounds__(256) void hist_kernel(const int* __restrict__ ei,
                                                   unsigned* __restrict__ hist, int E) {
    __shared__ unsigned lh[NB];
    if (threadIdx.x < NB) lh[threadIdx.x] = 0;
    __syncthreads();
    const int base = blockIdx.x * 4096;
#pragma unroll
    for (int j = 0; j < 16; ++j) {
        int e = base + j * 256 + threadIdx.x;
        if (e < E) atomicAdd(&lh[(unsigned)ei[E + e] >> BSH], 1u);
    }
    __syncthreads();
    if (threadIdx.x < NB && lh[threadIdx.x]) atomicAdd(&hist[threadIdx.x], lh[threadIdx.x]);
}

// ---------------- K2: one-wave exclusive scan over NB bucket counts ----------------
__global__ void bscan_kernel(const unsigned* __restrict__ hist, unsigned* __restrict__ boff,
                             unsigned* __restrict__ gcursor, int* __restrict__ row_ptr) {
    int lane = threadIdx.x & 63;
    unsigned v[4]; unsigned s = 0;
#pragma unroll
    for (int j = 0; j < 4; ++j) {
        int i = lane * 4 + j;
        v[j] = (i < NB) ? hist[i] : 0u;
        s += v[j];
    }
    unsigned e = s;
    for (int d = 1; d < 64; d <<= 1) {
        unsigned t = __shfl_up(e, d, 64);
        if (lane >= d) e += t;
    }
    e -= s;   // exclusive prefix of per-lane sums
    unsigned run = e;
#pragma unroll
    for (int j = 0; j < 4; ++j) {
        int i = lane * 4 + j;
        if (i < NB) { boff[i] = run; gcursor[i] = run; }
        run += v[j];
    }
    if (lane == 63) row_ptr[NN] = (int)run;   // = E
}

// ---------------- K3: bucketed scatter, LDS-staged chunk claims ----------------
__global__ __launch_bounds__(256) void scatter_kernel(const int* __restrict__ ei,
                                                      unsigned* __restrict__ gcursor,
                                                      unsigned* __restrict__ bedge, int E) {
    __shared__ unsigned rec[8192];
    __shared__ unsigned char bkt[8192];
    __shared__ unsigned lh[NB], cb[NB], lh2[NB];
    const int t = threadIdx.x;
    if (t < NB) { lh[t] = 0; lh2[t] = 0; }
    __syncthreads();
    const int base = blockIdx.x * 8192;
    const int cnt = min(8192, E - base);
#pragma unroll
    for (int j = 0; j < 32; ++j) {
        int k = j * 256 + t;
        if (k < cnt) {
            int e = base + k;
            unsigned s = (unsigned)ei[e];
            unsigned d = (unsigned)ei[E + e];
            unsigned b = d >> BSH;
            rec[k] = (s << 8) | (d & 255u);
            bkt[k] = (unsigned char)b;
            atomicAdd(&lh[b], 1u);
        }
    }
    __syncthreads();
    if (t < NB) cb[t] = lh[t] ? atomicAdd(&gcursor[t], lh[t]) : 0u;
    __syncthreads();
#pragma unroll
    for (int j = 0; j < 32; ++j) {
        int k = j * 256 + t;
        if (k < cnt) {
            unsigned b = bkt[k];
            unsigned r = atomicAdd(&lh2[b], 1u);
            bedge[cb[b] + r] = rec[k];
        }
    }
}

// ---------------- K4: per-bucket CSR build + deg + dis (one block per bucket) ----------------
__global__ __launch_bounds__(256) void csr_kernel(const unsigned* __restrict__ bedge,
                                                  const unsigned* __restrict__ boff,
                                                  const unsigned* __restrict__ bend,
                                                  int* __restrict__ row_ptr,
                                                  float* __restrict__ dis,
                                                  unsigned short* __restrict__ esrc) {
    __shared__ unsigned cnt[BNODES], woff[BNODES], cur[BNODES];
    __shared__ unsigned srec[8192];
    __shared__ unsigned short sout[8192];
    const int b = blockIdx.x;
    const unsigned base = boff[b];
    const unsigned end  = bend[b];
    const int ecnt = (int)(end - base);
    const int n0 = b * BNODES;
    const int nCnt = min(BNODES, NN - n0);
    const int t = threadIdx.x;
    cnt[t] = 0;
    __syncthreads();

    const bool fast = (ecnt <= 8192);
    if (fast) {
        for (int k = t; k < ecnt; k += 256) {
            unsigned r = bedge[base + k];
            srec[k] = r;
            atomicAdd(&cnt[r & 255u], 1u);
        }
    } else {
        for (int k = t; k < ecnt; k += 256) atomicAdd(&cnt[bedge[base + k] & 255u], 1u);
    }
    __syncthreads();
    if (t < 64) {
        unsigned v[4]; unsigned s = 0;
#pragma unroll
        for (int j = 0; j < 4; ++j) { v[j] = cnt[t * 4 + j]; s += v[j]; }
        unsigned e = s;
        for (int d = 1; d < 64; d <<= 1) {
            unsigned x = __shfl_up(e, d, 64);
            if (t >= d) e += x;
        }
        e -= s;
        unsigned run = e;
#pragma unroll
        for (int j = 0; j < 4; ++j) { woff[t * 4 + j] = run; run += v[j]; }
    }
    __syncthreads();
    if (t < nCnt) {
        row_ptr[n0 + t] = (int)(base + woff[t]);
        dis[n0 + t] = rsqrtf((float)(cnt[t] + 1u));
    }
    cur[t] = 0;
    __syncthreads();
    if (fast) {
        for (int k = t; k < ecnt; k += 256) {
            unsigned r = srec[k];
            unsigned dl = r & 255u;
            unsigned p = woff[dl] + atomicAdd(&cur[dl], 1u);
            sout[p] = (unsigned short)(r >> 8);
        }
        __syncthreads();
        for (int k = t; k < ecnt; k += 256) esrc[base + k] = sout[k];
    } else {
        for (int k = t; k < ecnt; k += 256) {
            unsigned r = bedge[base + k];
            unsigned dl = r & 255u;
            unsigned p = woff[dl] + atomicAdd(&cur[dl], 1u);
            esrc[base + p] = (unsigned short)(r >> 8);
        }
    }
}

// ---------------- GEMM: H1 = x @ W1 (f32 math, bf16x2-packed store) ----------------
__global__ __launch_bounds__(256, 2) void gemm1_kernel(const float* __restrict__ x,
                                                       const float* __restrict__ W1,
                                                       unsigned* __restrict__ H1b, int nRows) {
    __shared__ __align__(16) float w1t[128 * 128];
    __shared__ __align__(16) float xbuf[4][8][128];
    const int t = threadIdx.x;

    {
        const int c = t & 127;
        const int k0 = (t >> 7) * 64;
        char* wb = reinterpret_cast<char*>(w1t);
#pragma unroll
        for (int i = 0; i < 16; ++i) {
            int kk = k0 + i * 4;
            float4 w;
            w.x = W1[(kk + 0) * 128 + c];
            w.y = W1[(kk + 1) * 128 + c];
            w.z = W1[(kk + 2) * 128 + c];
            w.w = W1[(kk + 3) * 128 + c];
            int off = (c * 512 + kk * 4) ^ (((c >> 1) & 7) << 4);
            *reinterpret_cast<float4*>(wb + off) = w;
        }
    }

    const int wid = t >> 6, lane = t & 63;
    const long rowBase = (long)blockIdx.x * 32 + wid * 8;
    const bool haveRows = rowBase < nRows;

    if (haveRows) {
        const float4* gsrc = reinterpret_cast<const float4*>(x + rowBase * NF);
        float4* ldst = reinterpret_cast<float4*>(&xbuf[wid][0][0]);
#pragma unroll
        for (int i = 0; i < 4; ++i) ldst[i * 64 + lane] = gsrc[i * 64 + lane];
    }
    __syncthreads();
    if (!haveRows) return;

    const int c0 = 2 * lane;
    const char* wb = reinterpret_cast<const char*>(w1t);
    const float* xw = &xbuf[wid][0][0];
    float acc[8][2];
#pragma unroll
    for (int r = 0; r < 8; ++r) { acc[r][0] = 0.f; acc[r][1] = 0.f; }

    for (int kk = 0; kk < 128; kk += 4) {
        int offA = (c0 * 512 + kk * 4) ^ ((lane & 7) << 4);
        float4 wA = *reinterpret_cast<const float4*>(wb + offA);
        float4 wB = *reinterpret_cast<const float4*>(wb + offA + 512);
#pragma unroll
        for (int r = 0; r < 8; ++r) {
            float4 xv = *reinterpret_cast<const float4*>(xw + r * NF + kk);
            acc[r][0] = fmaf(xv.x, wA.x, acc[r][0]);
            acc[r][0] = fmaf(xv.y, wA.y, acc[r][0]);
            acc[r][0] = fmaf(xv.z, wA.z, acc[r][0]);
            acc[r][0] = fmaf(xv.w, wA.w, acc[r][0]);
            acc[r][1] = fmaf(xv.x, wB.x, acc[r][1]);
            acc[r][1] = fmaf(xv.y, wB.y, acc[r][1]);
            acc[r][1] = fmaf(xv.z, wB.z, acc[r][1]);
            acc[r][1] = fmaf(xv.w, wB.w, acc[r][1]);
        }
    }

#pragma unroll
    for (int r = 0; r < 8; ++r) {
        long row = rowBase + r;
        H1b[row * 64 + lane] = bf16rne(acc[r][0]) | (bf16rne(acc[r][1]) << 16);
    }
}

// ---------------- fused layer1 (bf16 gathers, half-wave per edge) ----------------
__global__ __launch_bounds__(256) void layer1_kernel(const unsigned* __restrict__ H1b,
                                                     const unsigned short* __restrict__ esrc,
                                                     const int* __restrict__ row_ptr,
                                                     const float* __restrict__ dis,
                                                     const float* __restrict__ b1,
                                                     const float* __restrict__ W2,
                                                     float* __restrict__ zd, int N) {
    const int v = (blockIdx.x * 256 + threadIdx.x) >> 6;
    if (v >= N) return;
    const int lane = threadIdx.x & 63;
    const int half = lane >> 5;
    const int sub = lane & 31;
    const int base = row_ptr[v];
    const int end  = row_ptr[v + 1];
    const char* hb = reinterpret_cast<const char*>(H1b);

    float a0 = 0.f, a1 = 0.f, a2 = 0.f, a3 = 0.f;

    for (int cb = base; cb < end; cb += 64) {
        const int m = min(64, end - cb);
        int es = 0; float ds_ = 0.f;
        if (cb + lane < end) {
            es = esrc[cb + lane];                  // coalesced ushort
            ds_ = dis[es];
        }
        const int pc = (m + 1) >> 1;
        int i = 0;
        for (; i + 8 <= pc; i += 8) {
            float w[8]; uint2 u[8];
#pragma unroll
            for (int j = 0; j < 8; ++j) {
                int idx = 2 * (i + j) + half;
                int sj = __shfl(es, idx);
                w[j] = __shfl(ds_, idx);
                u[j] = *reinterpret_cast<const uint2*>(hb + (size_t)(unsigned)sj * 256 + sub * 8);
            }
#pragma unroll
            for (int j = 0; j < 8; ++j) {
                a0 = fmaf(__uint_as_float(u[j].x << 16), w[j], a0);
                a1 = fmaf(__uint_as_float(u[j].x & 0xffff0000u), w[j], a1);
                a2 = fmaf(__uint_as_float(u[j].y << 16), w[j], a2);
                a3 = fmaf(__uint_as_float(u[j].y & 0xffff0000u), w[j], a3);
            }
        }
        for (; i < pc; ++i) {
            int idx = 2 * i + half;
            int sj = __shfl(es, idx);
            float wj = __shfl(ds_, idx);
            uint2 uj = *reinterpret_cast<const uint2*>(hb + (size_t)(unsigned)sj * 256 + sub * 8);
            a0 = fmaf(__uint_as_float(uj.x << 16), wj, a0);
            a1 = fmaf(__uint_as_float(uj.x & 0xffff0000u), wj, a1);
            a2 = fmaf(__uint_as_float(uj.y << 16), wj, a2);
            a3 = fmaf(__uint_as_float(uj.y & 0xffff0000u), wj, a3);
        }
    }

    a0 += __shfl_xor(a0, 32, 64);
    a1 += __shfl_xor(a1, 32, 64);
    a2 += __shfl_xor(a2, 32, 64);
    a3 += __shfl_xor(a3, 32, 64);

    const float dv = dis[v];
    const float sw = dv * dv;
    uint2 hs = *reinterpret_cast<const uint2*>(hb + (size_t)v * 256 + sub * 8);
    float4 bb = *reinterpret_cast<const float4*>(b1 + sub * 4);
    float4 w2 = *reinterpret_cast<const float4*>(W2 + sub * 4);
    float h0 = fmaf(dv, a0, fmaf(sw, __uint_as_float(hs.x << 16), bb.x));
    float h1 = fmaf(dv, a1, fmaf(sw, __uint_as_float(hs.x & 0xffff0000u), bb.y));
    float h2 = fmaf(dv, a2, fmaf(sw, __uint_as_float(hs.y << 16), bb.z));
    float h3 = fmaf(dv, a3, fmaf(sw, __uint_as_float(hs.y & 0xffff0000u), bb.w));
    h0 = h0 > 0.f ? h0 : 0.f;
    h1 = h1 > 0.f ? h1 : 0.f;
    h2 = h2 > 0.f ? h2 : 0.f;
    h3 = h3 > 0.f ? h3 : 0.f;
    float p = fmaf(h0, w2.x, fmaf(h1, w2.y, fmaf(h2, w2.z, h3 * w2.w)));
    for (int d = 1; d < 64; d <<= 1) p += __shfl_xor(p, d, 64);
    if (lane == 0) zd[v] = 0.5f * dv * p;
}

// ---------------- layer2 aggregate (scalar zd gather) + finalize ----------------
__global__ __launch_bounds__(256) void final_kernel(const float* __restrict__ zd,
                                                    const unsigned short* __restrict__ esrc,
                                                    const int* __restrict__ row_ptr,
                                                    const float* __restrict__ dis,
                                                    const float* __restrict__ b2,
                                                    float* __restrict__ out, int N) {
    const int g = (blockIdx.x * 256 + threadIdx.x) >> 3;
    if (g >= N) return;
    const int sl = threadIdx.x & 7;
    const int base = row_ptr[g];
    const int end  = row_ptr[g + 1];
    float acc = 0.f;
    for (int e = base + sl; e < end; e += 8) acc += zd[esrc[e]];
#pragma unroll
    for (int d = 1; d < 8; d <<= 1) acc += __shfl_xor(acc, d, 64);
    if (sl == 0) out[g] = fmaf(dis[g], acc + zd[g], b2[0]);
}

// ---------------- launch ----------------
extern "C" void kernel_launch(void* const* d_in, const int* in_sizes, int n_in,
                              void* d_out, int out_size, void* d_ws, size_t ws_size,
                              hipStream_t stream) {
    const float* x  = (const float*)d_in[0];
    const int*   ei = (const int*)d_in[1];
    const float* W1 = (const float*)d_in[2];
    const float* b1 = (const float*)d_in[3];
    const float* W2 = (const float*)d_in[4];
    const float* b2 = (const float*)d_in[5];
    float* out = (float*)d_out;

    char* ws = (char*)d_ws;
    size_t o = 0;
    auto alloc = [&](size_t bytes) -> void* {
        void* p = ws + o;
        o += (bytes + 255) & ~(size_t)255;
        return p;
    };
    unsigned* hist    = (unsigned*)alloc((size_t)NB * 4);
    unsigned* boff    = (unsigned*)alloc((size_t)(NB + 1) * 4);
    unsigned* gcursor = (unsigned*)alloc((size_t)NB * 4);
    float*    dis     = (float*)alloc((size_t)NN * 4);
    int*      row_ptr = (int*)alloc((size_t)(NN + 1) * 4);
    unsigned* bedge   = (unsigned*)alloc((size_t)NE * 4);
    unsigned short* esrc = (unsigned short*)alloc((size_t)NE * 2);
    float*    zd      = (float*)alloc((size_t)NN * 4);
    unsigned* H1b     = (unsigned*)alloc((size_t)NN * NF * 2);

    hipMemsetAsync(hist, 0, (size_t)NB * 4, stream);

    hist_kernel<<<(NE + 4095) / 4096, 256, 0, stream>>>(ei, hist, NE);
    bscan_kernel<<<1, 64, 0, stream>>>(hist, boff, gcursor, row_ptr);
    scatter_kernel<<<(NE + 8191) / 8192, 256, 0, stream>>>(ei, gcursor, bedge, NE);
    csr_kernel<<<NB, 256, 0, stream>>>(bedge, boff, gcursor, row_ptr, dis, esrc);

    gemm1_kernel<<<(NN + 31) / 32, 256, 0, stream>>>(x, W1, H1b, NN);

    layer1_kernel<<<(NN * 64 + 255) / 256, 256, 0, stream>>>(H1b, esrc, row_ptr, dis, b1, W2, zd, NN);

    final_kernel<<<(NN * 8 + 255) / 256, 256, 0, stream>>>(zd, esrc, row_ptr, dis, b2, out, NN);
}

// Round 5
// 115.244 us; speedup vs baseline: 2.0738x; 1.0695x over previous
//
#include <hip/hip_runtime.h>

// ---------------- problem constants ----------------
#define NN 50000
#define NE 800000
#define NF 128
#define NB 196        // ceil(NN/256) buckets of 256 nodes
#define BSH 8         // bucket = dst >> 8
#define BNODES 256

__device__ __forceinline__ unsigned bf16rne(float f) {
    unsigned u = __float_as_uint(f);
    return (u + 0x7FFFu + ((u >> 16) & 1u)) >> 16;
}

// ---------------- K0: zero the bucket histogram (replaces hipMemsetAsync) ----------------
__global__ void zero_kernel(unsigned* __restrict__ hist) {
    if (threadIdx.x < NB) hist[threadIdx.x] = 0;
}

// ---------------- K1: bucket histogram (LDS-binned) ----------------
__global__ __launch_bounds__(256) void hist_kernel(const int* __restrict__ ei,
                                                   unsigned* __restrict__ hist, int E) {
    __shared__ unsigned lh[NB];
    if (threadIdx.x < NB) lh[threadIdx.x] = 0;
    __syncthreads();
    const int base = blockIdx.x * 4096;
#pragma unroll
    for (int j = 0; j < 16; ++j) {
        int e = base + j * 256 + threadIdx.x;
        if (e < E) atomicAdd(&lh[(unsigned)ei[E + e] >> BSH], 1u);
    }
    __syncthreads();
    if (threadIdx.x < NB && lh[threadIdx.x]) atomicAdd(&hist[threadIdx.x], lh[threadIdx.x]);
}

// ---------------- K2: one-wave exclusive scan over NB bucket counts ----------------
__global__ void bscan_kernel(const unsigned* __restrict__ hist, unsigned* __restrict__ boff,
                             unsigned* __restrict__ gcursor, int* __restrict__ row_ptr) {
    int lane = threadIdx.x & 63;
    unsigned v[4]; unsigned s = 0;
#pragma unroll
    for (int j = 0; j < 4; ++j) {
        int i = lane * 4 + j;
        v[j] = (i < NB) ? hist[i] : 0u;
        s += v[j];
    }
    unsigned e = s;
    for (int d = 1; d < 64; d <<= 1) {
        unsigned t = __shfl_up(e, d, 64);
        if (lane >= d) e += t;
    }
    e -= s;   // exclusive prefix of per-lane sums
    unsigned run = e;
#pragma unroll
    for (int j = 0; j < 4; ++j) {
        int i = lane * 4 + j;
        if (i < NB) { boff[i] = run; gcursor[i] = run; }
        run += v[j];
    }
    if (lane == 63) row_ptr[NN] = (int)run;   // = E
}

// ---------------- K3: bucketed scatter, LDS-staged chunk claims ----------------
__global__ __launch_bounds__(256) void scatter_kernel(const int* __restrict__ ei,
                                                      unsigned* __restrict__ gcursor,
                                                      unsigned* __restrict__ bedge, int E) {
    __shared__ unsigned rec[8192];
    __shared__ unsigned char bkt[8192];
    __shared__ unsigned lh[NB], cb[NB], lh2[NB];
    const int t = threadIdx.x;
    if (t < NB) { lh[t] = 0; lh2[t] = 0; }
    __syncthreads();
    const int base = blockIdx.x * 8192;
    const int cnt = min(8192, E - base);
#pragma unroll
    for (int j = 0; j < 32; ++j) {
        int k = j * 256 + t;
        if (k < cnt) {
            int e = base + k;
            unsigned s = (unsigned)ei[e];
            unsigned d = (unsigned)ei[E + e];
            unsigned b = d >> BSH;
            rec[k] = (s << 8) | (d & 255u);
            bkt[k] = (unsigned char)b;
            atomicAdd(&lh[b], 1u);
        }
    }
    __syncthreads();
    if (t < NB) cb[t] = lh[t] ? atomicAdd(&gcursor[t], lh[t]) : 0u;
    __syncthreads();
#pragma unroll
    for (int j = 0; j < 32; ++j) {
        int k = j * 256 + t;
        if (k < cnt) {
            unsigned b = bkt[k];
            unsigned r = atomicAdd(&lh2[b], 1u);
            bedge[cb[b] + r] = rec[k];
        }
    }
}

// ---------------- K4: per-bucket CSR build + deg + dis (one block per bucket) ----------------
__global__ __launch_bounds__(256) void csr_kernel(const unsigned* __restrict__ bedge,
                                                  const unsigned* __restrict__ boff,
                                                  const unsigned* __restrict__ bend,
                                                  int* __restrict__ row_ptr,
                                                  float* __restrict__ dis,
                                                  unsigned short* __restrict__ esrc) {
    __shared__ unsigned cnt[BNODES], woff[BNODES], cur[BNODES];
    __shared__ unsigned srec[8192];
    __shared__ unsigned short sout[8192];
    const int b = blockIdx.x;
    const unsigned base = boff[b];
    const unsigned end  = bend[b];
    const int ecnt = (int)(end - base);
    const int n0 = b * BNODES;
    const int nCnt = min(BNODES, NN - n0);
    const int t = threadIdx.x;
    cnt[t] = 0;
    __syncthreads();

    const bool fast = (ecnt <= 8192);
    if (fast) {
        for (int k = t; k < ecnt; k += 256) {
            unsigned r = bedge[base + k];
            srec[k] = r;
            atomicAdd(&cnt[r & 255u], 1u);
        }
    } else {
        for (int k = t; k < ecnt; k += 256) atomicAdd(&cnt[bedge[base + k] & 255u], 1u);
    }
    __syncthreads();
    if (t < 64) {
        unsigned v[4]; unsigned s = 0;
#pragma unroll
        for (int j = 0; j < 4; ++j) { v[j] = cnt[t * 4 + j]; s += v[j]; }
        unsigned e = s;
        for (int d = 1; d < 64; d <<= 1) {
            unsigned x = __shfl_up(e, d, 64);
            if (t >= d) e += x;
        }
        e -= s;
        unsigned run = e;
#pragma unroll
        for (int j = 0; j < 4; ++j) { woff[t * 4 + j] = run; run += v[j]; }
    }
    __syncthreads();
    if (t < nCnt) {
        row_ptr[n0 + t] = (int)(base + woff[t]);
        dis[n0 + t] = rsqrtf((float)(cnt[t] + 1u));
    }
    cur[t] = 0;
    __syncthreads();
    if (fast) {
        for (int k = t; k < ecnt; k += 256) {
            unsigned r = srec[k];
            unsigned dl = r & 255u;
            unsigned p = woff[dl] + atomicAdd(&cur[dl], 1u);
            sout[p] = (unsigned short)(r >> 8);
        }
        __syncthreads();
        for (int k = t; k < ecnt; k += 256) esrc[base + k] = sout[k];
    } else {
        for (int k = t; k < ecnt; k += 256) {
            unsigned r = bedge[base + k];
            unsigned dl = r & 255u;
            unsigned p = woff[dl] + atomicAdd(&cur[dl], 1u);
            esrc[base + p] = (unsigned short)(r >> 8);
        }
    }
}

// ---------------- GEMM: H1 = x @ W1 (f32 math, bf16x2-packed store) ----------------
// K-tiled x2: LDS = W1 half-panel [64][128] native layout (32KB) + xbuf[4][8][64] (8KB)
// = 40KB -> 4 blocks/CU = 16 waves/CU. Lane owns col pair {2l,2l+1}: w-read is a
// conflict-free ds_read_b64 (bank = 2l%32, 2 lanes/bank = free); x-reads are
// wave-uniform b128 broadcasts. No transpose, no swizzle.
__global__ __launch_bounds__(256, 4) void gemm1_kernel(const float* __restrict__ x,
                                                       const float* __restrict__ W1,
                                                       unsigned* __restrict__ H1b, int nRows) {
    __shared__ __align__(16) float w1t[64 * 128];    // 32KB, K-half of W1, [k][c]
    __shared__ __align__(16) float xbuf[4][8][64];   // 8KB
    const int t = threadIdx.x;
    const int wid = t >> 6, lane = t & 63;
    const long rowBase = (long)blockIdx.x * 32 + wid * 8;
    const bool haveRows = rowBase < nRows;   // NN % 8 == 0 -> whole-wave granularity
    const int c0 = 2 * lane;

    float acc[8][2];
#pragma unroll
    for (int r = 0; r < 8; ++r) { acc[r][0] = 0.f; acc[r][1] = 0.f; }

    for (int p = 0; p < 2; ++p) {
        // stage W1 rows [p*64, p*64+64) -- straight coalesced copy, no transpose
        {
            const float4* wg = reinterpret_cast<const float4*>(W1 + p * 64 * NF);
            float4* wl = reinterpret_cast<float4*>(w1t);
#pragma unroll
            for (int i = 0; i < 8; ++i) wl[i * 256 + t] = wg[i * 256 + t];
        }
        // stage this wave's 8 x-rows, k-half p
        if (haveRows) {
#pragma unroll
            for (int i = 0; i < 2; ++i) {
                int j = i * 64 + lane;          // 0..127
                int r = j >> 4, q = j & 15;     // 16 float4 per row-half
                reinterpret_cast<float4*>(&xbuf[wid][r][0])[q] =
                    reinterpret_cast<const float4*>(x + (rowBase + r) * NF + p * 64)[q];
            }
        }
        __syncthreads();

        if (haveRows) {
            for (int kk = 0; kk < 64; kk += 4) {
                float2 wv0 = *reinterpret_cast<const float2*>(w1t + (kk + 0) * NF + c0);
                float2 wv1 = *reinterpret_cast<const float2*>(w1t + (kk + 1) * NF + c0);
                float2 wv2 = *reinterpret_cast<const float2*>(w1t + (kk + 2) * NF + c0);
                float2 wv3 = *reinterpret_cast<const float2*>(w1t + (kk + 3) * NF + c0);
#pragma unroll
                for (int r = 0; r < 8; ++r) {
                    float4 xv = *reinterpret_cast<const float4*>(&xbuf[wid][r][kk]);
                    acc[r][0] = fmaf(xv.x, wv0.x, acc[r][0]);
                    acc[r][1] = fmaf(xv.x, wv0.y, acc[r][1]);
                    acc[r][0] = fmaf(xv.y, wv1.x, acc[r][0]);
                    acc[r][1] = fmaf(xv.y, wv1.y, acc[r][1]);
                    acc[r][0] = fmaf(xv.z, wv2.x, acc[r][0]);
                    acc[r][1] = fmaf(xv.z, wv2.y, acc[r][1]);
                    acc[r][0] = fmaf(xv.w, wv3.x, acc[r][0]);
                    acc[r][1] = fmaf(xv.w, wv3.y, acc[r][1]);
                }
            }
        }
        __syncthreads();   // before next pass overwrites LDS
    }

    if (!haveRows) return;
#pragma unroll
    for (int r = 0; r < 8; ++r) {
        long row = rowBase + r;
        H1b[row * 64 + lane] = bf16rne(acc[r][0]) | (bf16rne(acc[r][1]) << 16);
    }
}

// ---------------- fused layer1 (bf16 gathers, half-wave per edge) ----------------
__global__ __launch_bounds__(256) void layer1_kernel(const unsigned* __restrict__ H1b,
                                                     const unsigned short* __restrict__ esrc,
                                                     const int* __restrict__ row_ptr,
                                                     const float* __restrict__ dis,
                                                     const float* __restrict__ b1,
                                                     const float* __restrict__ W2,
                                                     float* __restrict__ zd, int N) {
    const int v = (blockIdx.x * 256 + threadIdx.x) >> 6;
    if (v >= N) return;
    const int lane = threadIdx.x & 63;
    const int half = lane >> 5;
    const int sub = lane & 31;
    const int base = row_ptr[v];
    const int end  = row_ptr[v + 1];
    const char* hb = reinterpret_cast<const char*>(H1b);

    float a0 = 0.f, a1 = 0.f, a2 = 0.f, a3 = 0.f;

    for (int cb = base; cb < end; cb += 64) {
        const int m = min(64, end - cb);
        int es = 0; float ds_ = 0.f;
        if (cb + lane < end) {
            es = esrc[cb + lane];                  // coalesced ushort
            ds_ = dis[es];
        }
        const int pc = (m + 1) >> 1;
        int i = 0;
        for (; i + 8 <= pc; i += 8) {
            float w[8]; uint2 u[8];
#pragma unroll
            for (int j = 0; j < 8; ++j) {
                int idx = 2 * (i + j) + half;
                int sj = __shfl(es, idx);
                w[j] = __shfl(ds_, idx);
                u[j] = *reinterpret_cast<const uint2*>(hb + (size_t)(unsigned)sj * 256 + sub * 8);
            }
#pragma unroll
            for (int j = 0; j < 8; ++j) {
                a0 = fmaf(__uint_as_float(u[j].x << 16), w[j], a0);
                a1 = fmaf(__uint_as_float(u[j].x & 0xffff0000u), w[j], a1);
                a2 = fmaf(__uint_as_float(u[j].y << 16), w[j], a2);
                a3 = fmaf(__uint_as_float(u[j].y & 0xffff0000u), w[j], a3);
            }
        }
        for (; i < pc; ++i) {
            int idx = 2 * i + half;
            int sj = __shfl(es, idx);
            float wj = __shfl(ds_, idx);
            uint2 uj = *reinterpret_cast<const uint2*>(hb + (size_t)(unsigned)sj * 256 + sub * 8);
            a0 = fmaf(__uint_as_float(uj.x << 16), wj, a0);
            a1 = fmaf(__uint_as_float(uj.x & 0xffff0000u), wj, a1);
            a2 = fmaf(__uint_as_float(uj.y << 16), wj, a2);
            a3 = fmaf(__uint_as_float(uj.y & 0xffff0000u), wj, a3);
        }
    }

    a0 += __shfl_xor(a0, 32, 64);
    a1 += __shfl_xor(a1, 32, 64);
    a2 += __shfl_xor(a2, 32, 64);
    a3 += __shfl_xor(a3, 32, 64);

    const float dv = dis[v];
    const float sw = dv * dv;
    uint2 hs = *reinterpret_cast<const uint2*>(hb + (size_t)v * 256 + sub * 8);
    float4 bb = *reinterpret_cast<const float4*>(b1 + sub * 4);
    float4 w2 = *reinterpret_cast<const float4*>(W2 + sub * 4);
    float h0 = fmaf(dv, a0, fmaf(sw, __uint_as_float(hs.x << 16), bb.x));
    float h1 = fmaf(dv, a1, fmaf(sw, __uint_as_float(hs.x & 0xffff0000u), bb.y));
    float h2 = fmaf(dv, a2, fmaf(sw, __uint_as_float(hs.y << 16), bb.z));
    float h3 = fmaf(dv, a3, fmaf(sw, __uint_as_float(hs.y & 0xffff0000u), bb.w));
    h0 = h0 > 0.f ? h0 : 0.f;
    h1 = h1 > 0.f ? h1 : 0.f;
    h2 = h2 > 0.f ? h2 : 0.f;
    h3 = h3 > 0.f ? h3 : 0.f;
    float p = fmaf(h0, w2.x, fmaf(h1, w2.y, fmaf(h2, w2.z, h3 * w2.w)));
    for (int d = 1; d < 64; d <<= 1) p += __shfl_xor(p, d, 64);
    if (lane == 0) zd[v] = 0.5f * dv * p;
}

// ---------------- layer2 aggregate (scalar zd gather) + finalize ----------------
__global__ __launch_bounds__(256) void final_kernel(const float* __restrict__ zd,
                                                    const unsigned short* __restrict__ esrc,
                                                    const int* __restrict__ row_ptr,
                                                    const float* __restrict__ dis,
                                                    const float* __restrict__ b2,
                                                    float* __restrict__ out, int N) {
    const int g = (blockIdx.x * 256 + threadIdx.x) >> 3;
    if (g >= N) return;
    const int sl = threadIdx.x & 7;
    const int base = row_ptr[g];
    const int end  = row_ptr[g + 1];
    float acc = 0.f;
    for (int e = base + sl; e < end; e += 8) acc += zd[esrc[e]];
#pragma unroll
    for (int d = 1; d < 8; d <<= 1) acc += __shfl_xor(acc, d, 64);
    if (sl == 0) out[g] = fmaf(dis[g], acc + zd[g], b2[0]);
}

// ---------------- launch ----------------
extern "C" void kernel_launch(void* const* d_in, const int* in_sizes, int n_in,
                              void* d_out, int out_size, void* d_ws, size_t ws_size,
                              hipStream_t stream) {
    const float* x  = (const float*)d_in[0];
    const int*   ei = (const int*)d_in[1];
    const float* W1 = (const float*)d_in[2];
    const float* b1 = (const float*)d_in[3];
    const float* W2 = (const float*)d_in[4];
    const float* b2 = (const float*)d_in[5];
    float* out = (float*)d_out;

    char* ws = (char*)d_ws;
    size_t o = 0;
    auto alloc = [&](size_t bytes) -> void* {
        void* p = ws + o;
        o += (bytes + 255) & ~(size_t)255;
        return p;
    };
    unsigned* hist    = (unsigned*)alloc((size_t)NB * 4);
    unsigned* boff    = (unsigned*)alloc((size_t)(NB + 1) * 4);
    unsigned* gcursor = (unsigned*)alloc((size_t)NB * 4);
    float*    dis     = (float*)alloc((size_t)NN * 4);
    int*      row_ptr = (int*)alloc((size_t)(NN + 1) * 4);
    unsigned* bedge   = (unsigned*)alloc((size_t)NE * 4);
    unsigned short* esrc = (unsigned short*)alloc((size_t)NE * 2);
    float*    zd      = (float*)alloc((size_t)NN * 4);
    unsigned* H1b     = (unsigned*)alloc((size_t)NN * NF * 2);

    zero_kernel<<<1, 256, 0, stream>>>(hist);
    hist_kernel<<<(NE + 4095) / 4096, 256, 0, stream>>>(ei, hist, NE);
    bscan_kernel<<<1, 64, 0, stream>>>(hist, boff, gcursor, row_ptr);
    scatter_kernel<<<(NE + 8191) / 8192, 256, 0, stream>>>(ei, gcursor, bedge, NE);
    csr_kernel<<<NB, 256, 0, stream>>>(bedge, boff, gcursor, row_ptr, dis, esrc);

    gemm1_kernel<<<(NN + 31) / 32, 256, 0, stream>>>(x, W1, H1b, NN);

    layer1_kernel<<<(NN * 64 + 255) / 256, 256, 0, stream>>>(H1b, esrc, row_ptr, dis, b1, W2, zd, NN);

    final_kernel<<<(NN * 8 + 255) / 256, 256, 0, stream>>>(zd, esrc, row_ptr, dis, b2, out, NN);
}